// Round 3
// baseline (8149.746 us; speedup 1.0000x reference)
//
#include <hip/hip_runtime.h>
#include <cstdint>
#include <cstddef>

#define NB 256   // batch
#define NT 512   // time steps
#define ND 64    // input dim
#define NH 512   // hidden dim

typedef __attribute__((ext_vector_type(8))) short short8;
typedef __attribute__((ext_vector_type(4))) float f32x4;

__device__ __forceinline__ unsigned short f2bf(float f) {
  union { float f; uint32_t u; } v; v.f = f;
  uint32_t u = v.u;
  return (unsigned short)((u + 0x7FFFu + ((u >> 16) & 1u)) >> 16);  // RNE
}
__device__ __forceinline__ float bf2f(unsigned short b) {
  union { uint32_t u; float f; } v; v.u = ((uint32_t)b) << 16;
  return v.f;
}
__device__ __forceinline__ void split8(const float* v, short8& hi, short8& lo) {
#pragma unroll
  for (int e = 0; e < 8; ++e) {
    unsigned short hb = f2bf(v[e]);
    hi[e] = (short)hb;
    lo[e] = (short)f2bf(v[e] - bf2f(hb));
  }
}

// Per-call init: out = b_ho, zero h buffer 0 (both planes), zero flags.
__global__ void init_kernel(const float* __restrict__ bho, float* __restrict__ out,
                            unsigned int* __restrict__ hzero, unsigned int* __restrict__ flags) {
  int i = blockIdx.x * 256 + threadIdx.x;
  if (i < NB * NT) out[i] = bho[0];
  if (i < (2 * NB * NH * 2) / 4) hzero[i] = 0u;   // buf0 hi+lo planes as u32
  if (i < 4096) flags[i] = 0u;
}

// Persistent RNN: 64 blocks x 4 waves (256 thr, 1 block/CU due to 128KB LDS).
// Block = (bg, cb): bg = 16 batch rows (16 groups), cb = 128 hidden cols (4 chunks).
// Wave w owns 32 cols: W_hh hi-plane stationary in VGPRs (128), lo-plane in LDS
// (fragment-major, conflict-free). Sync: per-bg 4-block flag handshake
// (release store + relaxed sc1 spin, no RMW). XCD-affinity bid mapping.
__global__ __launch_bounds__(256, 1) void rnn_persist(
    const float* __restrict__ x, const float* __restrict__ wih,
    const float* __restrict__ whh, const float* __restrict__ bih,
    const float* __restrict__ bhh, const float* __restrict__ who,
    unsigned short* __restrict__ hbuf,   // [2][2 planes][NB*NH] u16
    unsigned int* __restrict__ flags,    // [16 bg][4 cb] u32, 128B apart
    float* __restrict__ out)
{
  __shared__ short8 wlo_lds[4][2][16][64];   // 128 KiB, [wave][nt][kt][lane]

  const int bid  = blockIdx.x;
  const int c    = bid & 7;                  // XCD under round-robin
  const int kk   = bid >> 3;                 // 0..7
  const int bg   = c * 2 + (kk & 1);         // 0..15, peers share c -> same XCD
  const int cb   = kk >> 1;                  // 0..3
  const int w    = threadIdx.x >> 6;         // wave 0..3
  const int lane = threadIdx.x & 63;
  const int lm   = lane & 15;
  const int lg   = lane >> 4;
  const int lkb  = lg * 8;
  const int bm   = bg * 16;
  const int n0   = cb * 128 + w * 32;

  // ---- prologue: stage stationary weights ----
  short8 wh_hi[2][16];                 // W_hh hi B-frags (128 VGPR)
  short8 wx_hi[2][2], wx_lo[2][2];     // W_ih B-frags (32 VGPR)
  float  bv[2], wov[2];
#pragma unroll
  for (int nt = 0; nt < 2; ++nt) {
    const int n = n0 + nt * 16 + lm;
    bv[nt]  = bih[n] + bhh[n];
    wov[nt] = who[n];
#pragma unroll
    for (int kt = 0; kt < 16; ++kt) {
      float v[8];
      const float* p = whh + (size_t)n * NH + kt * 32 + lkb;
      *(f32x4*)&v[0] = *(const f32x4*)p;
      *(f32x4*)&v[4] = *(const f32x4*)(p + 4);
      short8 lo;
      split8(v, wh_hi[nt][kt], lo);
      wlo_lds[w][nt][kt][lane] = lo;   // own region, own wave: no barrier needed
    }
#pragma unroll
    for (int kt = 0; kt < 2; ++kt) {
      float v[8];
      const float* p = wih + (size_t)n * ND + kt * 32 + lkb;
      *(f32x4*)&v[0] = *(const f32x4*)p;
      *(f32x4*)&v[4] = *(const f32x4*)(p + 4);
      split8(v, wx_hi[nt][kt], wx_lo[nt][kt]);
    }
  }

  // x(0) raw prefetch
  const float* xrow = x + (size_t)(bm + lm) * NT * ND + lkb;
  f32x4 xr[4];
#pragma unroll
  for (int xt = 0; xt < 2; ++xt) {
    xr[2 * xt]     = *(const f32x4*)(xrow + xt * 32);
    xr[2 * xt + 1] = *(const f32x4*)(xrow + xt * 32 + 4);
  }

  unsigned int* fl = flags + bg * 128;

  for (int t = 0; t < NT; ++t) {
    // ---- wait for peers' h(t-1) ----
    if (t > 0) {
      const unsigned tgt = (unsigned)t;
      const bool need = (lane < 4) && (lane != cb);
      const unsigned int* fp = fl + lane * 32;
      for (;;) {
        unsigned v = tgt;
        if (need) v = __hip_atomic_load(fp, __ATOMIC_RELAXED, __HIP_MEMORY_SCOPE_AGENT);
        if (__all(v >= tgt)) break;
        __builtin_amdgcn_s_sleep(1);
      }
      __threadfence();   // acquire: invalidate caches before reading peer h
    }

    // convert x(t) raw -> split A-frags, then issue x(t+1) prefetch
    short8 ax_hi[2], ax_lo[2];
#pragma unroll
    for (int xt = 0; xt < 2; ++xt) {
      float v[8];
      *(f32x4*)&v[0] = xr[2 * xt];
      *(f32x4*)&v[4] = xr[2 * xt + 1];
      split8(v, ax_hi[xt], ax_lo[xt]);
    }
    if (t + 1 < NT) {
#pragma unroll
      for (int xt = 0; xt < 2; ++xt) {
        xr[2 * xt]     = *(const f32x4*)(xrow + (size_t)(t + 1) * ND + xt * 32);
        xr[2 * xt + 1] = *(const f32x4*)(xrow + (size_t)(t + 1) * ND + xt * 32 + 4);
      }
    }

    const unsigned short* ph_hi = hbuf + (size_t)(t & 1) * (2 * NB * NH);
    const unsigned short* ph_lo = ph_hi + (size_t)NB * NH;
    unsigned short* nx_hi = hbuf + (size_t)((t + 1) & 1) * (2 * NB * NH);
    unsigned short* nx_lo = nx_hi + (size_t)NB * NH;

    f32x4 acc[2][3];
#pragma unroll
    for (int nt = 0; nt < 2; ++nt)
#pragma unroll
      for (int s = 0; s < 3; ++s) acc[nt][s] = (f32x4){0.f, 0.f, 0.f, 0.f};

    // ---- K loop: h(t-1) A-frags from global, B hi from VGPR, B lo from LDS ----
    const unsigned short* arow_hi = ph_hi + (size_t)(bm + lm) * NH + lkb;
    const unsigned short* arow_lo = ph_lo + (size_t)(bm + lm) * NH + lkb;
#pragma unroll
    for (int kt = 0; kt < 16; ++kt) {
      short8 ah = *(const short8*)(arow_hi + kt * 32);
      short8 al = *(const short8*)(arow_lo + kt * 32);
#pragma unroll
      for (int nt = 0; nt < 2; ++nt) {
        short8 bl = wlo_lds[w][nt][kt][lane];
        acc[nt][0] = __builtin_amdgcn_mfma_f32_16x16x32_bf16(ah, wh_hi[nt][kt], acc[nt][0], 0, 0, 0);
        acc[nt][1] = __builtin_amdgcn_mfma_f32_16x16x32_bf16(ah, bl,            acc[nt][1], 0, 0, 0);
        acc[nt][2] = __builtin_amdgcn_mfma_f32_16x16x32_bf16(al, wh_hi[nt][kt], acc[nt][2], 0, 0, 0);
      }
    }
#pragma unroll
    for (int xt = 0; xt < 2; ++xt)
#pragma unroll
      for (int nt = 0; nt < 2; ++nt) {
        acc[nt][0] = __builtin_amdgcn_mfma_f32_16x16x32_bf16(ax_hi[xt], wx_hi[nt][xt], acc[nt][0], 0, 0, 0);
        acc[nt][1] = __builtin_amdgcn_mfma_f32_16x16x32_bf16(ax_hi[xt], wx_lo[nt][xt], acc[nt][1], 0, 0, 0);
        acc[nt][2] = __builtin_amdgcn_mfma_f32_16x16x32_bf16(ax_lo[xt], wx_hi[nt][xt], acc[nt][2], 0, 0, 0);
      }

    // ---- epilogue: tanh + split-store h(t) ----
    float po[4] = {0.f, 0.f, 0.f, 0.f};
#pragma unroll
    for (int nt = 0; nt < 2; ++nt) {
#pragma unroll
      for (int r = 0; r < 4; ++r) {
        float pre = acc[nt][0][r] + acc[nt][1][r] + acc[nt][2][r] + bv[nt];
        float hv  = tanhf(pre);
        const int m = lg * 4 + r;
        const size_t idx = (size_t)(bm + m) * NH + n0 + nt * 16 + lm;
        unsigned short hb = f2bf(hv);
        nx_hi[idx] = hb;
        nx_lo[idx] = f2bf(hv - bf2f(hb));
        po[r] += hv * wov[nt];
      }
    }

    // ---- publish: fence own stores, block-sync, release flag ----
    __threadfence();
    __syncthreads();
    if (threadIdx.x == 0)
      __hip_atomic_store(fl + cb * 32, (unsigned)(t + 1), __ATOMIC_RELEASE,
                         __HIP_MEMORY_SCOPE_AGENT);

    // ---- out projection: off the critical path (peers already released) ----
#pragma unroll
    for (int s = 1; s < 16; s <<= 1)
#pragma unroll
      for (int r = 0; r < 4; ++r) po[r] += __shfl_xor(po[r], s, 64);
    if (lm == 0) {
#pragma unroll
      for (int r = 0; r < 4; ++r)
        atomicAdd(&out[(size_t)(bm + lg * 4 + r) * NT + t], po[r]);
    }
  }
}

extern "C" void kernel_launch(void* const* d_in, const int* in_sizes, int n_in,
                              void* d_out, int out_size, void* d_ws, size_t ws_size,
                              hipStream_t stream) {
  const float* x   = (const float*)d_in[0];
  const float* wih = (const float*)d_in[1];
  const float* whh = (const float*)d_in[2];
  const float* bih = (const float*)d_in[3];
  const float* bhh = (const float*)d_in[4];
  const float* who = (const float*)d_in[5];
  const float* bho = (const float*)d_in[6];
  float* out = (float*)d_out;

  // ws: hbuf[2][2 planes][NB*NH] u16 (1 MB), then flags (16 KB)
  unsigned short* hbuf = (unsigned short*)d_ws;
  unsigned int* flags = (unsigned int*)(hbuf + (size_t)2 * 2 * NB * NH);

  init_kernel<<<(NB * NT + 255) / 256, 256, 0, stream>>>(
      bho, out, (unsigned int*)hbuf, flags);

  rnn_persist<<<64, 256, 0, stream>>>(x, wih, whh, bih, bhh, who, hbuf, flags, out);
}

// Round 4
// 5076.364 us; speedup vs baseline: 1.6054x; 1.6054x over previous
//
#include <hip/hip_runtime.h>
#include <cstdint>
#include <cstddef>

#define NB 256   // batch
#define NT 512   // time steps
#define ND 64    // input dim
#define NH 512   // hidden dim

typedef __attribute__((ext_vector_type(8))) short short8;
typedef __attribute__((ext_vector_type(4))) float f32x4;
typedef unsigned long long ull;

__device__ __forceinline__ unsigned short f2bf(float f) {
  union { float f; uint32_t u; } v; v.f = f;
  uint32_t u = v.u;
  return (unsigned short)((u + 0x7FFFu + ((u >> 16) & 1u)) >> 16);  // RNE
}
__device__ __forceinline__ float bf2f(unsigned short b) {
  union { uint32_t u; float f; } v; v.u = ((uint32_t)b) << 16;
  return v.f;
}
__device__ __forceinline__ void split8(const float* v, short8& hi, short8& lo) {
#pragma unroll
  for (int e = 0; e < 8; ++e) {
    unsigned short hb = f2bf(v[e]);
    hi[e] = (short)hb;
    lo[e] = (short)f2bf(v[e] - bf2f(hb));
  }
}
__device__ __forceinline__ float tanh_fast(float x) {
  float ax = fabsf(x);
  float e  = __expf(-2.0f * ax);            // v_exp based, branch-free
  float t  = (1.0f - e) * __frcp_rn(1.0f + e);
  return copysignf(t, x);
}

// Per-call init: out = b_ho, zero h buffer 0 (both planes), zero flags.
__global__ void init_kernel(const float* __restrict__ bho, float* __restrict__ out,
                            unsigned int* __restrict__ hzero, unsigned int* __restrict__ flags) {
  int i = blockIdx.x * 256 + threadIdx.x;
  if (i < NB * NT) out[i] = bho[0];
  if (i < (2 * NB * NH * 2) / 4) hzero[i] = 0u;   // buf0 hi+lo planes as u32
  if (i < 4096) flags[i] = 0u;
}

// Persistent RNN: 64 blocks x 4 waves. Block = (bg, cb):
//   bg = 16 batch rows (16 groups), cb = 128 hidden cols (4 chunks).
// W_hh hi-plane stationary in VGPR/AGPR, lo-plane in LDS.
// Cross-block h exchange via relaxed AGENT-scope atomic stores/loads
// (write-through / read-through the IF coherence point) -- NO cache fences.
__global__ __launch_bounds__(256, 1) void rnn_persist(
    const float* __restrict__ x, const float* __restrict__ wih,
    const float* __restrict__ whh, const float* __restrict__ bih,
    const float* __restrict__ bhh, const float* __restrict__ who,
    unsigned short* __restrict__ hbuf,   // [2][2 planes][NB*NH] u16
    unsigned int* __restrict__ flags,    // [16 bg][4 cb] u32, 128B apart
    float* __restrict__ out)
{
  __shared__ short8 wlo_lds[4][2][16][64];           // 128 KiB
  __shared__ unsigned short hstage[4][2][16][40];    // 10 KiB (pad 40 vs 32)

  const int bid  = blockIdx.x;
  const int bg   = bid >> 2;                 // 0..15
  const int cb   = bid & 3;                  // 0..3
  const int w    = threadIdx.x >> 6;         // wave 0..3
  const int lane = threadIdx.x & 63;
  const int lm   = lane & 15;
  const int lg   = lane >> 4;
  const int lkb  = lg * 8;
  const int bm   = bg * 16;
  const int n0   = cb * 128 + w * 32;        // wave's 32-col base

  // ---- prologue: stationary weights ----
  short8 wh_hi[2][16];                 // W_hh hi B-frags
  short8 wx_hi[2][2], wx_lo[2][2];     // W_ih B-frags
  float  bv[2], wov[2];
#pragma unroll
  for (int nt = 0; nt < 2; ++nt) {
    const int n = n0 + nt * 16 + lm;
    bv[nt]  = bih[n] + bhh[n];
    wov[nt] = who[n];
#pragma unroll
    for (int kt = 0; kt < 16; ++kt) {
      float v[8];
      const float* p = whh + (size_t)n * NH + kt * 32 + lkb;
      *(f32x4*)&v[0] = *(const f32x4*)p;
      *(f32x4*)&v[4] = *(const f32x4*)(p + 4);
      short8 lo;
      split8(v, wh_hi[nt][kt], lo);
      wlo_lds[w][nt][kt][lane] = lo;   // own wave's region only
    }
#pragma unroll
    for (int kt = 0; kt < 2; ++kt) {
      float v[8];
      const float* p = wih + (size_t)n * ND + kt * 32 + lkb;
      *(f32x4*)&v[0] = *(const f32x4*)p;
      *(f32x4*)&v[4] = *(const f32x4*)(p + 4);
      split8(v, wx_hi[nt][kt], wx_lo[nt][kt]);
    }
  }

  // x(0) raw prefetch
  const float* xrow = x + (size_t)(bm + lm) * NT * ND + lkb;
  f32x4 xr[4];
#pragma unroll
  for (int xt = 0; xt < 2; ++xt) {
    xr[2 * xt]     = *(const f32x4*)(xrow + xt * 32);
    xr[2 * xt + 1] = *(const f32x4*)(xrow + xt * 32 + 4);
  }

  unsigned int* fl = flags + bg * 128;

  for (int t = 0; t < NT; ++t) {
    // ---- x(t): convert + x-MFMAs BEFORE the wait (independent of h) ----
    short8 ax_hi[2], ax_lo[2];
#pragma unroll
    for (int xt = 0; xt < 2; ++xt) {
      float v[8];
      *(f32x4*)&v[0] = xr[2 * xt];
      *(f32x4*)&v[4] = xr[2 * xt + 1];
      split8(v, ax_hi[xt], ax_lo[xt]);
    }
    f32x4 acc[2][3];
#pragma unroll
    for (int nt = 0; nt < 2; ++nt)
#pragma unroll
      for (int s = 0; s < 3; ++s) acc[nt][s] = (f32x4){0.f, 0.f, 0.f, 0.f};
#pragma unroll
    for (int xt = 0; xt < 2; ++xt)
#pragma unroll
      for (int nt = 0; nt < 2; ++nt) {
        acc[nt][0] = __builtin_amdgcn_mfma_f32_16x16x32_bf16(ax_hi[xt], wx_hi[nt][xt], acc[nt][0], 0, 0, 0);
        acc[nt][1] = __builtin_amdgcn_mfma_f32_16x16x32_bf16(ax_hi[xt], wx_lo[nt][xt], acc[nt][1], 0, 0, 0);
        acc[nt][2] = __builtin_amdgcn_mfma_f32_16x16x32_bf16(ax_lo[xt], wx_hi[nt][xt], acc[nt][2], 0, 0, 0);
      }

    // ---- wait for peers' h(t-1) flags (relaxed polls, no fences) ----
    if (t > 0) {
      const unsigned tgt = (unsigned)t;
      const bool need = (lane < 4) && (lane != cb);
      const unsigned int* fp = fl + lane * 32;
      for (;;) {
        unsigned v = tgt;
        if (need) v = __hip_atomic_load(fp, __ATOMIC_RELAXED, __HIP_MEMORY_SCOPE_AGENT);
        if (__all(v >= tgt)) break;
        __builtin_amdgcn_s_sleep(2);
      }
      asm volatile("" ::: "memory");   // keep h loads below the spin
    }

    const unsigned short* ph_hi = hbuf + (size_t)(t & 1) * (2 * NB * NH);
    const unsigned short* ph_lo = ph_hi + (size_t)NB * NH;
    unsigned short* nx_hi = hbuf + (size_t)((t + 1) & 1) * (2 * NB * NH);
    unsigned short* nx_lo = nx_hi + (size_t)NB * NH;

    // ---- K loop: h(t-1) A-frags via agent-scope loads (IF-coherent) ----
    const size_t abase = (size_t)(bm + lm) * NH + lkb;
#pragma unroll
    for (int kt = 0; kt < 16; ++kt) {
      const ull* pa = (const ull*)(ph_hi + abase + kt * 32);
      const ull* pb = (const ull*)(ph_lo + abase + kt * 32);
      union { ull q[2]; short8 s; } ua, ub;
      ua.q[0] = __hip_atomic_load(pa + 0, __ATOMIC_RELAXED, __HIP_MEMORY_SCOPE_AGENT);
      ua.q[1] = __hip_atomic_load(pa + 1, __ATOMIC_RELAXED, __HIP_MEMORY_SCOPE_AGENT);
      ub.q[0] = __hip_atomic_load(pb + 0, __ATOMIC_RELAXED, __HIP_MEMORY_SCOPE_AGENT);
      ub.q[1] = __hip_atomic_load(pb + 1, __ATOMIC_RELAXED, __HIP_MEMORY_SCOPE_AGENT);
#pragma unroll
      for (int nt = 0; nt < 2; ++nt) {
        short8 bl = wlo_lds[w][nt][kt][lane];
        acc[nt][0] = __builtin_amdgcn_mfma_f32_16x16x32_bf16(ua.s, wh_hi[nt][kt], acc[nt][0], 0, 0, 0);
        acc[nt][1] = __builtin_amdgcn_mfma_f32_16x16x32_bf16(ua.s, bl,            acc[nt][1], 0, 0, 0);
        acc[nt][2] = __builtin_amdgcn_mfma_f32_16x16x32_bf16(ub.s, wh_hi[nt][kt], acc[nt][2], 0, 0, 0);
      }
    }

    // ---- epilogue: tanh, stage fragments to LDS (own wave region) ----
    float po[4] = {0.f, 0.f, 0.f, 0.f};
#pragma unroll
    for (int nt = 0; nt < 2; ++nt) {
#pragma unroll
      for (int r = 0; r < 4; ++r) {
        float pre = acc[nt][0][r] + acc[nt][1][r] + acc[nt][2][r] + bv[nt];
        float hv  = tanh_fast(pre);
        const int m = lg * 4 + r;
        unsigned short hb = f2bf(hv);
        hstage[w][0][m][nt * 16 + lm] = hb;
        hstage[w][1][m][nt * 16 + lm] = f2bf(hv - bf2f(hb));
        po[r] += hv * wov[nt];
      }
    }

    // ---- publish: wide agent-scope write-through stores (no dirty L2) ----
    {
      const int prow = lane >> 2;            // 0..15
      const int pc   = (lane & 3) * 8;       // 0,8,16,24 (u16 units)
#pragma unroll
      for (int p = 0; p < 2; ++p) {
        union { f32x4 v; ull q[2]; } uu;
        uu.v = *(const f32x4*)&hstage[w][p][prow][pc];
        unsigned short* base = p ? nx_lo : nx_hi;
        ull* dst = (ull*)(base + (size_t)(bm + prow) * NH + n0 + pc);
        __hip_atomic_store(dst + 0, uu.q[0], __ATOMIC_RELAXED, __HIP_MEMORY_SCOPE_AGENT);
        __hip_atomic_store(dst + 1, uu.q[1], __ATOMIC_RELAXED, __HIP_MEMORY_SCOPE_AGENT);
      }
    }
    asm volatile("s_waitcnt vmcnt(0)" ::: "memory");  // stores at coherence point
    __syncthreads();                                   // all 4 waves drained
    if (threadIdx.x == 0)
      __hip_atomic_store(fl + cb * 32, (unsigned)(t + 1), __ATOMIC_RELAXED,
                         __HIP_MEMORY_SCOPE_AGENT);

    // ---- off critical path: x(t+1) prefetch, out projection ----
    if (t + 1 < NT) {
#pragma unroll
      for (int xt = 0; xt < 2; ++xt) {
        xr[2 * xt]     = *(const f32x4*)(xrow + (size_t)(t + 1) * ND + xt * 32);
        xr[2 * xt + 1] = *(const f32x4*)(xrow + (size_t)(t + 1) * ND + xt * 32 + 4);
      }
    }
#pragma unroll
    for (int s = 1; s < 16; s <<= 1)
#pragma unroll
      for (int r = 0; r < 4; ++r) po[r] += __shfl_xor(po[r], s, 64);
    if (lm == 0) {
#pragma unroll
      for (int r = 0; r < 4; ++r)
        atomicAdd(&out[(size_t)(bm + lg * 4 + r) * NT + t], po[r]);
    }
  }
}

extern "C" void kernel_launch(void* const* d_in, const int* in_sizes, int n_in,
                              void* d_out, int out_size, void* d_ws, size_t ws_size,
                              hipStream_t stream) {
  const float* x   = (const float*)d_in[0];
  const float* wih = (const float*)d_in[1];
  const float* whh = (const float*)d_in[2];
  const float* bih = (const float*)d_in[3];
  const float* bhh = (const float*)d_in[4];
  const float* who = (const float*)d_in[5];
  const float* bho = (const float*)d_in[6];
  float* out = (float*)d_out;

  // ws: hbuf[2][2 planes][NB*NH] u16 (1 MB), then flags (16 KB)
  unsigned short* hbuf = (unsigned short*)d_ws;
  unsigned int* flags = (unsigned int*)(hbuf + (size_t)2 * 2 * NB * NH);

  init_kernel<<<(NB * NT + 255) / 256, 256, 0, stream>>>(
      bho, out, (unsigned int*)hbuf, flags);

  rnn_persist<<<64, 256, 0, stream>>>(x, wih, whh, bih, bhh, who, hbuf, flags, out);
}

// Round 6
// 4707.352 us; speedup vs baseline: 1.7313x; 1.0784x over previous
//
#include <hip/hip_runtime.h>
#include <cstdint>
#include <cstddef>

#define NB 256   // batch
#define NT 512   // time steps
#define ND 64    // input dim
#define NH 512   // hidden dim

typedef __attribute__((ext_vector_type(8))) short short8;
typedef __attribute__((ext_vector_type(4))) float f32x4;
typedef unsigned long long ull;

__device__ __forceinline__ unsigned short f2bf(float f) {
  union { float f; uint32_t u; } v; v.f = f;
  uint32_t u = v.u;
  return (unsigned short)((u + 0x7FFFu + ((u >> 16) & 1u)) >> 16);  // RNE
}
__device__ __forceinline__ float bf2f(unsigned short b) {
  union { uint32_t u; float f; } v; v.u = ((uint32_t)b) << 16;
  return v.f;
}
__device__ __forceinline__ void split8(const float* v, short8& hi, short8& lo) {
#pragma unroll
  for (int e = 0; e < 8; ++e) {
    unsigned short hb = f2bf(v[e]);
    hi[e] = (short)hb;
    lo[e] = (short)f2bf(v[e] - bf2f(hb));
  }
}
__device__ __forceinline__ float tanh_fast(float x) {
  float ax = fabsf(x);
  float e  = __expf(-2.0f * ax);
  float t  = (1.0f - e) * __frcp_rn(1.0f + e);
  return copysignf(t, x);
}

// Per-call init: out = b_ho, zero h buf0 (both planes), zero flags.
__global__ void init_kernel(const float* __restrict__ bho, float* __restrict__ out,
                            unsigned int* __restrict__ hzero, unsigned int* __restrict__ flags) {
  int i = blockIdx.x * 256 + threadIdx.x;
  if (i < NB * NT) out[i] = bho[0];
  if (i < (2 * NB * NH * 2) / 4) hzero[i] = 0u;   // buf0 hi+lo planes as u32
  if (i < 2048) flags[i] = 0u;
}

// Persistent RNN: 64 blocks x 4 waves. Block = (bg, cb):
//   bg = 16 batch rows (16 groups), cb = 128 hidden cols (4 chunks).
// W_hh hi-plane stationary in VGPRs, lo-plane in LDS.
// Cross-block h exchange: relaxed AGENT-scope atomics (IF-coherent, proven in R4).
// R6 changes vs R4: (1) batch-issue ALL peer h loads before any consumer
// (one IF latency instead of 16), (2) own 128 cols read from double-buffered
// LDS hstage instead of IF, (3) no sc0/getreg fast path (R5 hang).
__global__ __launch_bounds__(256, 1) void rnn_persist(
    const float* __restrict__ x, const float* __restrict__ wih,
    const float* __restrict__ whh, const float* __restrict__ bih,
    const float* __restrict__ bhh, const float* __restrict__ who,
    unsigned short* __restrict__ hbuf,   // [2][2 planes][NB*NH] u16
    unsigned int* __restrict__ flags,    // [16 bg][4 cb] u32, 128B apart
    float* __restrict__ out)
{
  __shared__ short8 wlo_lds[4][2][16][64];                       // 128 KiB
  __shared__ __align__(16) unsigned short hstage[2][4][2][16][40]; // 20 KiB dbuf

  const int bid  = blockIdx.x;
  const int bg   = bid >> 2;                 // 0..15
  const int cb   = bid & 3;                  // 0..3
  const int w    = threadIdx.x >> 6;
  const int lane = threadIdx.x & 63;
  const int lm   = lane & 15;
  const int lg   = lane >> 4;
  const int lkb  = lg * 8;
  const int bm   = bg * 16;
  const int n0   = cb * 128 + w * 32;

  // ---- prologue: stationary weights ----
  short8 wh_hi[2][16];
  short8 wx_hi[2][2], wx_lo[2][2];
  float  bv[2], wov[2];
#pragma unroll
  for (int nt = 0; nt < 2; ++nt) {
    const int n = n0 + nt * 16 + lm;
    bv[nt]  = bih[n] + bhh[n];
    wov[nt] = who[n];
#pragma unroll
    for (int kt = 0; kt < 16; ++kt) {
      float v[8];
      const float* p = whh + (size_t)n * NH + kt * 32 + lkb;
      *(f32x4*)&v[0] = *(const f32x4*)p;
      *(f32x4*)&v[4] = *(const f32x4*)(p + 4);
      short8 lo;
      split8(v, wh_hi[nt][kt], lo);
      wlo_lds[w][nt][kt][lane] = lo;         // own-wave region only
    }
#pragma unroll
    for (int kt = 0; kt < 2; ++kt) {
      float v[8];
      const float* p = wih + (size_t)n * ND + kt * 32 + lkb;
      *(f32x4*)&v[0] = *(const f32x4*)p;
      *(f32x4*)&v[4] = *(const f32x4*)(p + 4);
      split8(v, wx_hi[nt][kt], wx_lo[nt][kt]);
    }
  }

  // zero hstage buffer 0 (h(-1) own-col fragments), then one barrier
  for (int i = threadIdx.x; i < 2560; i += 256) ((unsigned*)hstage)[i] = 0u;
  __syncthreads();

  // x(0) raw prefetch
  const float* xrow = x + (size_t)(bm + lm) * NT * ND + lkb;
  f32x4 xr[4];
#pragma unroll
  for (int xt = 0; xt < 2; ++xt) {
    xr[2 * xt]     = *(const f32x4*)(xrow + xt * 32);
    xr[2 * xt + 1] = *(const f32x4*)(xrow + xt * 32 + 4);
  }

  unsigned int* fl = flags + bg * 128;

  for (int t = 0; t < NT; ++t) {
    const unsigned short* ph_hi = hbuf + (size_t)(t & 1) * (2 * NB * NH);
    const unsigned short* ph_lo = ph_hi + (size_t)NB * NH;
    unsigned short* nx_hi = hbuf + (size_t)((t + 1) & 1) * (2 * NB * NH);
    unsigned short* nx_lo = nx_hi + (size_t)NB * NH;

    // ---- x(t): convert + x-MFMAs BEFORE the wait (hidden under flag prop) ----
    short8 ax_hi[2], ax_lo[2];
#pragma unroll
    for (int xt = 0; xt < 2; ++xt) {
      float v[8];
      *(f32x4*)&v[0] = xr[2 * xt];
      *(f32x4*)&v[4] = xr[2 * xt + 1];
      split8(v, ax_hi[xt], ax_lo[xt]);
    }
    f32x4 acc[2][3];
#pragma unroll
    for (int nt = 0; nt < 2; ++nt)
#pragma unroll
      for (int s = 0; s < 3; ++s) acc[nt][s] = (f32x4){0.f, 0.f, 0.f, 0.f};
#pragma unroll
    for (int xt = 0; xt < 2; ++xt)
#pragma unroll
      for (int nt = 0; nt < 2; ++nt) {
        acc[nt][0] = __builtin_amdgcn_mfma_f32_16x16x32_bf16(ax_hi[xt], wx_hi[nt][xt], acc[nt][0], 0, 0, 0);
        acc[nt][1] = __builtin_amdgcn_mfma_f32_16x16x32_bf16(ax_hi[xt], wx_lo[nt][xt], acc[nt][1], 0, 0, 0);
        acc[nt][2] = __builtin_amdgcn_mfma_f32_16x16x32_bf16(ax_lo[xt], wx_hi[nt][xt], acc[nt][2], 0, 0, 0);
      }

    // ---- own 128 cols: A-frags from LDS hstage (written at step t-1) ----
    short8 hh[16], hl[16];
#pragma unroll
    for (int kk = 0; kk < 4; ++kk) {
      // ktg = cb*4 + kk handled below via uniform branch; preload nothing here
    }

    // ---- wait for peers' h(t-1) flags ----
    if (t > 0) {
      const unsigned tgt = (unsigned)t;
      const bool need = (lane < 4) && (lane != cb);
      const unsigned int* fp = fl + lane * 32;
      for (;;) {
        unsigned v = tgt;
        if (need) v = __hip_atomic_load(fp, __ATOMIC_RELAXED, __HIP_MEMORY_SCOPE_AGENT);
        if (__all(v >= tgt)) break;
        __builtin_amdgcn_s_sleep(2);
      }
      asm volatile("" ::: "memory");   // keep h loads below the spin
    }

    // ---- batch-issue ALL h(t-1) A-frag loads (peer: IF, own: LDS) ----
    const size_t abase = (size_t)(bm + lm) * NH + lkb;
#pragma unroll
    for (int ktg = 0; ktg < 16; ++ktg) {
      if ((ktg >> 2) == cb) {
        // own tile: from LDS double buffer
        hh[ktg] = *(const short8*)&hstage[t & 1][ktg & 3][0][lm][lkb];
        hl[ktg] = *(const short8*)&hstage[t & 1][ktg & 3][1][lm][lkb];
      } else {
        const ull* pa = (const ull*)(ph_hi + abase + ktg * 32);
        const ull* pb = (const ull*)(ph_lo + abase + ktg * 32);
        union { ull q[2]; short8 s; } ua, ub;
        ua.q[0] = __hip_atomic_load(pa + 0, __ATOMIC_RELAXED, __HIP_MEMORY_SCOPE_AGENT);
        ua.q[1] = __hip_atomic_load(pa + 1, __ATOMIC_RELAXED, __HIP_MEMORY_SCOPE_AGENT);
        ub.q[0] = __hip_atomic_load(pb + 0, __ATOMIC_RELAXED, __HIP_MEMORY_SCOPE_AGENT);
        ub.q[1] = __hip_atomic_load(pb + 1, __ATOMIC_RELAXED, __HIP_MEMORY_SCOPE_AGENT);
        hh[ktg] = ua.s;
        hl[ktg] = ub.s;
      }
    }

    // ---- MFMA main loop (consumers after all issues -> one latency) ----
#pragma unroll
    for (int ktg = 0; ktg < 16; ++ktg) {
#pragma unroll
      for (int nt = 0; nt < 2; ++nt) {
        short8 bl = wlo_lds[w][nt][ktg][lane];
        acc[nt][0] = __builtin_amdgcn_mfma_f32_16x16x32_bf16(hh[ktg], wh_hi[nt][ktg], acc[nt][0], 0, 0, 0);
        acc[nt][1] = __builtin_amdgcn_mfma_f32_16x16x32_bf16(hh[ktg], bl,             acc[nt][1], 0, 0, 0);
        acc[nt][2] = __builtin_amdgcn_mfma_f32_16x16x32_bf16(hl[ktg], wh_hi[nt][ktg], acc[nt][2], 0, 0, 0);
      }
    }

    // ---- epilogue: tanh, stage fragments to LDS (next step's own tiles) ----
    float po[4] = {0.f, 0.f, 0.f, 0.f};
#pragma unroll
    for (int nt = 0; nt < 2; ++nt) {
#pragma unroll
      for (int r = 0; r < 4; ++r) {
        float pre = acc[nt][0][r] + acc[nt][1][r] + acc[nt][2][r] + bv[nt];
        float hv  = tanh_fast(pre);
        const int m = lg * 4 + r;
        unsigned short hb = f2bf(hv);
        hstage[(t + 1) & 1][w][0][m][nt * 16 + lm] = hb;
        hstage[(t + 1) & 1][w][1][m][nt * 16 + lm] = f2bf(hv - bf2f(hb));
        po[r] += hv * wov[nt];
      }
    }

    // ---- publish h(t): wide agent-scope stores (IF-coherent) ----
    {
      const int prow = lane >> 2;            // 0..15
      const int pc   = (lane & 3) * 8;       // u16 units
#pragma unroll
      for (int p = 0; p < 2; ++p) {
        union { f32x4 v; ull q[2]; } uu;
        uu.v = *(const f32x4*)&hstage[(t + 1) & 1][w][p][prow][pc];
        unsigned short* base = p ? nx_lo : nx_hi;
        ull* dst = (ull*)(base + (size_t)(bm + prow) * NH + n0 + pc);
        __hip_atomic_store(dst + 0, uu.q[0], __ATOMIC_RELAXED, __HIP_MEMORY_SCOPE_AGENT);
        __hip_atomic_store(dst + 1, uu.q[1], __ATOMIC_RELAXED, __HIP_MEMORY_SCOPE_AGENT);
      }
    }
    asm volatile("s_waitcnt vmcnt(0)" ::: "memory");  // h at the coherence point
    __syncthreads();                                   // all 4 waves drained
    if (threadIdx.x == 0)
      __hip_atomic_store(fl + cb * 32, (unsigned)(t + 1), __ATOMIC_RELAXED,
                         __HIP_MEMORY_SCOPE_AGENT);

    // ---- off critical path: x(t+1) prefetch, out projection ----
    if (t + 1 < NT) {
#pragma unroll
      for (int xt = 0; xt < 2; ++xt) {
        xr[2 * xt]     = *(const f32x4*)(xrow + (size_t)(t + 1) * ND + xt * 32);
        xr[2 * xt + 1] = *(const f32x4*)(xrow + (size_t)(t + 1) * ND + xt * 32 + 4);
      }
    }
#pragma unroll
    for (int s = 1; s < 16; s <<= 1)
#pragma unroll
      for (int r = 0; r < 4; ++r) po[r] += __shfl_xor(po[r], s, 64);
    if (lm == 0) {
#pragma unroll
      for (int r = 0; r < 4; ++r)
        atomicAdd(&out[(size_t)(bm + lg * 4 + r) * NT + t], po[r]);
    }
  }
}

extern "C" void kernel_launch(void* const* d_in, const int* in_sizes, int n_in,
                              void* d_out, int out_size, void* d_ws, size_t ws_size,
                              hipStream_t stream) {
  const float* x   = (const float*)d_in[0];
  const float* wih = (const float*)d_in[1];
  const float* whh = (const float*)d_in[2];
  const float* bih = (const float*)d_in[3];
  const float* bhh = (const float*)d_in[4];
  const float* who = (const float*)d_in[5];
  const float* bho = (const float*)d_in[6];
  float* out = (float*)d_out;

  // ws: hbuf[2][2 planes][NB*NH] u16 (1 MB), then flags (8 KB)
  unsigned short* hbuf = (unsigned short*)d_ws;
  unsigned int* flags = (unsigned int*)(hbuf + (size_t)2 * 2 * NB * NH);

  init_kernel<<<(NB * NT + 255) / 256, 256, 0, stream>>>(
      bho, out, (unsigned int*)hbuf, flags);

  rnn_persist<<<64, 256, 0, stream>>>(x, wih, whh, bih, bhh, who, hbuf, flags, out);
}

// Round 7
// 2666.903 us; speedup vs baseline: 3.0559x; 1.7651x over previous
//
#include <hip/hip_runtime.h>
#include <cstdint>
#include <cstddef>

#define NB 256   // batch
#define NT 512   // time steps
#define ND 64    // input dim
#define NH 512   // hidden dim

typedef __attribute__((ext_vector_type(8))) short short8;
typedef __attribute__((ext_vector_type(4))) float f32x4;
typedef unsigned long long ull;

__device__ __forceinline__ unsigned short f2bf(float f) {
  union { float f; uint32_t u; } v; v.f = f;
  uint32_t u = v.u;
  return (unsigned short)((u + 0x7FFFu + ((u >> 16) & 1u)) >> 16);  // RNE
}
__device__ __forceinline__ float bf2f(unsigned short b) {
  union { uint32_t u; float f; } v; v.u = ((uint32_t)b) << 16;
  return v.f;
}
__device__ __forceinline__ void split8(const float* v, short8& hi, short8& lo) {
#pragma unroll
  for (int e = 0; e < 8; ++e) {
    unsigned short hb = f2bf(v[e]);
    hi[e] = (short)hb;
    lo[e] = (short)f2bf(v[e] - bf2f(hb));
  }
}
__device__ __forceinline__ float tanh_fast(float x) {
  float ax = fabsf(x);
  float e  = __expf(-2.0f * ax);
  float t  = (1.0f - e) * __frcp_rn(1.0f + e);
  return copysignf(t, x);
}

// Zero h buffer 0 (both planes, chunk layout) and the flags.
__global__ void init_kernel(unsigned int* __restrict__ hzero,
                            unsigned int* __restrict__ flags) {
  int i = blockIdx.x * 256 + threadIdx.x;
  if (i < 131072) hzero[i] = 0u;   // buf0: 16bg*16gk*2p*512 u16 = 131072 u32
  if (i < 4096) flags[i] = 0u;
}

// out[b][t] = b_ho + sum_cb partial[cb][b][t]
__global__ void combine_kernel(const float* __restrict__ partial,
                               const float* __restrict__ bho,
                               float* __restrict__ out) {
  int id = blockIdx.x * 256 + threadIdx.x;   // b*NT + t, 131072 total
  out[id] = bho[0] + partial[id] + partial[id + NB * NT]
          + partial[id + 2 * NB * NT] + partial[id + 3 * NB * NT];
}

// Persistent RNN: 64 blocks x 4 waves. Block = (bg, cb):
//   bg = 16 batch rows (16 groups), cb = 128 hidden cols (4 chunks).
// h published CHUNK-CONTIGUOUS per 32-col K-tile (gk): [16 rows][32 cols]
// hi then lo plane, 1KB each. Wave w fetches gk = w*4..w*4+3 (coalesced,
// deduplicated across waves), stages in LDS hpeer; hi/lo consumed in two
// passes through a single-plane hpeer to fit LDS. Per-(bg,gk) flags.
// Out projection: LDS partial reduce + ONE plain store (no atomics).
__global__ __launch_bounds__(256, 1) void rnn_persist(
    const float* __restrict__ x, const float* __restrict__ wih,
    const float* __restrict__ whh, const float* __restrict__ bih,
    const float* __restrict__ bhh, const float* __restrict__ who,
    unsigned short* __restrict__ hbuf,   // [2][16 bg][16 gk][2 p][512] u16
    unsigned int* __restrict__ flags,    // [16 bg][16 gk][16] u32 (64B apart)
    float* __restrict__ partial)         // [4 cb][NB][NT] f32
{
  __shared__ short8 wlo_lds[4][2][16][64];            // 128 KiB
  __shared__ unsigned short hpeer[16][16][36];        // 18 KiB (one plane)
  __shared__ unsigned short tstage[4][2][16][36];     // 9 KiB (per-wave)
  __shared__ float posum[4][16];                      // 256 B

  const int bid  = blockIdx.x;
  const int bg   = bid >> 2;                 // 0..15
  const int cb   = bid & 3;                  // 0..3
  const int w    = threadIdx.x >> 6;
  const int lane = threadIdx.x & 63;
  const int lm   = lane & 15;
  const int lg   = lane >> 4;
  const int lkb  = lg * 8;
  const int bm   = bg * 16;
  const int n0   = cb * 128 + w * 32;
  const int gko  = cb * 4 + w;               // chunk this wave publishes

  // ---- prologue: stationary weights ----
  short8 wh_hi[2][16];
  short8 wx_hi[2][2], wx_lo[2][2];
  float  bv[2], wov[2];
#pragma unroll
  for (int nt = 0; nt < 2; ++nt) {
    const int n = n0 + nt * 16 + lm;
    bv[nt]  = bih[n] + bhh[n];
    wov[nt] = who[n];
#pragma unroll
    for (int s = 0; s < 16; ++s) {
      float v[8];
      const float* p = whh + (size_t)n * NH + s * 32 + lkb;
      *(f32x4*)&v[0] = *(const f32x4*)p;
      *(f32x4*)&v[4] = *(const f32x4*)(p + 4);
      short8 lo;
      split8(v, wh_hi[nt][s], lo);
      wlo_lds[w][nt][s][lane] = lo;          // own-wave region only
    }
#pragma unroll
    for (int kt = 0; kt < 2; ++kt) {
      float v[8];
      const float* p = wih + (size_t)n * ND + kt * 32 + lkb;
      *(f32x4*)&v[0] = *(const f32x4*)p;
      *(f32x4*)&v[4] = *(const f32x4*)(p + 4);
      split8(v, wx_hi[nt][kt], wx_lo[nt][kt]);
    }
  }
  __syncthreads();

  // x(0) raw prefetch
  const float* xrow = x + (size_t)(bm + lm) * NT * ND + lkb;
  f32x4 xr[4];
#pragma unroll
  for (int xt = 0; xt < 2; ++xt) {
    xr[2 * xt]     = *(const f32x4*)(xrow + xt * 32);
    xr[2 * xt + 1] = *(const f32x4*)(xrow + xt * 32 + 4);
  }

  unsigned int* flbase = flags + bg * 256;
  unsigned int* myflag = flbase + gko * 16;

  for (int t = 0; t < NT; ++t) {
    const int cur = t & 1;
    const size_t bb = (size_t)cur * 262144 + (size_t)bg * 16384;  // u16 units

    // ---- x(t): convert before the wait ----
    short8 ax_hi[2], ax_lo[2];
#pragma unroll
    for (int xt = 0; xt < 2; ++xt) {
      float v[8];
      *(f32x4*)&v[0] = xr[2 * xt];
      *(f32x4*)&v[4] = xr[2 * xt + 1];
      split8(v, ax_hi[xt], ax_lo[xt]);
    }

    // ---- spin on my 4 assigned chunk flags (lanes 0..3) ----
    {
      const unsigned tgt = (unsigned)t;
      const unsigned int* fp = flbase + (w * 4 + (lane & 3)) * 16;
      for (;;) {
        unsigned v = tgt;
        if (lane < 4) v = __hip_atomic_load(fp, __ATOMIC_RELAXED, __HIP_MEMORY_SCOPE_AGENT);
        if (__all(v >= tgt)) break;
        __builtin_amdgcn_s_sleep(1);
      }
      asm volatile("" ::: "memory");
    }

    // ---- issue all 16 fetch loads: 4 chunks x (hi,lo) x 2 ull, coalesced ----
    ull fq[4][4];
#pragma unroll
    for (int i = 0; i < 4; ++i) {
      const int gk = w * 4 + i;
      const ull* ph = (const ull*)(hbuf + bb + (size_t)(gk * 2 + 0) * 512);
      const ull* pl = (const ull*)(hbuf + bb + (size_t)(gk * 2 + 1) * 512);
      fq[i][0] = __hip_atomic_load(ph + lane * 2,     __ATOMIC_RELAXED, __HIP_MEMORY_SCOPE_AGENT);
      fq[i][1] = __hip_atomic_load(ph + lane * 2 + 1, __ATOMIC_RELAXED, __HIP_MEMORY_SCOPE_AGENT);
      fq[i][2] = __hip_atomic_load(pl + lane * 2,     __ATOMIC_RELAXED, __HIP_MEMORY_SCOPE_AGENT);
      fq[i][3] = __hip_atomic_load(pl + lane * 2 + 1, __ATOMIC_RELAXED, __HIP_MEMORY_SCOPE_AGENT);
    }

    // ---- x MFMAs while the fetch flies ----
    f32x4 acc[2][3];
#pragma unroll
    for (int nt = 0; nt < 2; ++nt)
#pragma unroll
      for (int s = 0; s < 3; ++s) acc[nt][s] = (f32x4){0.f, 0.f, 0.f, 0.f};
#pragma unroll
    for (int xt = 0; xt < 2; ++xt)
#pragma unroll
      for (int nt = 0; nt < 2; ++nt) {
        acc[nt][0] = __builtin_amdgcn_mfma_f32_16x16x32_bf16(ax_hi[xt], wx_hi[nt][xt], acc[nt][0], 0, 0, 0);
        acc[nt][1] = __builtin_amdgcn_mfma_f32_16x16x32_bf16(ax_hi[xt], wx_lo[nt][xt], acc[nt][1], 0, 0, 0);
        acc[nt][2] = __builtin_amdgcn_mfma_f32_16x16x32_bf16(ax_lo[xt], wx_hi[nt][xt], acc[nt][2], 0, 0, 0);
      }

    // ---- stage hi plane to hpeer ----
#pragma unroll
    for (int i = 0; i < 4; ++i) {
      ull* d = (ull*)&hpeer[w * 4 + i][lane >> 2][(lane & 3) * 8];
      d[0] = fq[i][0]; d[1] = fq[i][1];
    }
    __syncthreads();   // A1: hi ready

    // ---- pass 1: ah x (W_hi -> acc0, W_lo -> acc1), 16 chunks ----
#pragma unroll
    for (int s = 0; s < 16; ++s) {
      union { ull q[2]; short8 v; } ua;
      const ull* ap = (const ull*)&hpeer[s][lm][lkb];
      ua.q[0] = ap[0]; ua.q[1] = ap[1];
#pragma unroll
      for (int nt = 0; nt < 2; ++nt) {
        short8 bl = wlo_lds[w][nt][s][lane];
        acc[nt][0] = __builtin_amdgcn_mfma_f32_16x16x32_bf16(ua.v, wh_hi[nt][s], acc[nt][0], 0, 0, 0);
        acc[nt][1] = __builtin_amdgcn_mfma_f32_16x16x32_bf16(ua.v, bl,           acc[nt][1], 0, 0, 0);
      }
    }
    __syncthreads();   // A2: hi reads done

    // x(t+1) prefetch (consumed next iteration, drained by publish vmcnt)
    if (t + 1 < NT) {
#pragma unroll
      for (int xt = 0; xt < 2; ++xt) {
        xr[2 * xt]     = *(const f32x4*)(xrow + (size_t)(t + 1) * ND + xt * 32);
        xr[2 * xt + 1] = *(const f32x4*)(xrow + (size_t)(t + 1) * ND + xt * 32 + 4);
      }
    }

    // ---- stage lo plane to hpeer ----
#pragma unroll
    for (int i = 0; i < 4; ++i) {
      ull* d = (ull*)&hpeer[w * 4 + i][lane >> 2][(lane & 3) * 8];
      d[0] = fq[i][2]; d[1] = fq[i][3];
    }
    __syncthreads();   // A3: lo ready

    // ---- pass 2: al x W_hi -> acc2 ----
#pragma unroll
    for (int s = 0; s < 16; ++s) {
      union { ull q[2]; short8 v; } ua;
      const ull* ap = (const ull*)&hpeer[s][lm][lkb];
      ua.q[0] = ap[0]; ua.q[1] = ap[1];
#pragma unroll
      for (int nt = 0; nt < 2; ++nt)
        acc[nt][2] = __builtin_amdgcn_mfma_f32_16x16x32_bf16(ua.v, wh_hi[nt][s], acc[nt][2], 0, 0, 0);
    }

    // ---- epilogue: tanh, split, transpose-stage, out partials ----
    float po[4] = {0.f, 0.f, 0.f, 0.f};
#pragma unroll
    for (int nt = 0; nt < 2; ++nt) {
#pragma unroll
      for (int r = 0; r < 4; ++r) {
        float pre = acc[nt][0][r] + acc[nt][1][r] + acc[nt][2][r] + bv[nt];
        float hv  = tanh_fast(pre);
        const int m = lg * 4 + r;
        unsigned short hb = f2bf(hv);
        tstage[w][0][m][nt * 16 + lm] = hb;
        tstage[w][1][m][nt * 16 + lm] = f2bf(hv - bf2f(hb));
        po[r] += hv * wov[nt];
      }
    }
#pragma unroll
    for (int s = 1; s < 16; s <<= 1)
#pragma unroll
      for (int r = 0; r < 4; ++r) po[r] += __shfl_xor(po[r], s, 64);
    if (lm == 0) {
#pragma unroll
      for (int r = 0; r < 4; ++r) posum[w][lg * 4 + r] = po[r];
    }

    // ---- publish own chunk (row-major 1KB hi + 1KB lo), then flag ----
    {
      const size_t ob = (size_t)(cur ^ 1) * 262144 + (size_t)bg * 16384
                      + (size_t)(gko * 2) * 512;
#pragma unroll
      for (int p = 0; p < 2; ++p) {
        const ull* sp = (const ull*)&tstage[w][p][lane >> 2][(lane & 3) * 8];
        ull q0 = sp[0], q1 = sp[1];
        ull* dst = (ull*)(hbuf + ob + (size_t)p * 512) + lane * 2;
        __hip_atomic_store(dst,     q0, __ATOMIC_RELAXED, __HIP_MEMORY_SCOPE_AGENT);
        __hip_atomic_store(dst + 1, q1, __ATOMIC_RELAXED, __HIP_MEMORY_SCOPE_AGENT);
      }
    }
    asm volatile("s_waitcnt vmcnt(0)" ::: "memory");   // h at coherence point
    if (lane == 0)
      __hip_atomic_store(myflag, (unsigned)(t + 1), __ATOMIC_RELAXED,
                         __HIP_MEMORY_SCOPE_AGENT);
    __syncthreads();   // B: posum complete, hpeer reads done

    // ---- out partial: ONE plain store per block-step (no atomics) ----
    if (w == 0 && lane < 16) {
      float s4 = posum[0][lane] + posum[1][lane] + posum[2][lane] + posum[3][lane];
      partial[((size_t)cb * NB + bm + lane) * NT + t] = s4;
    }
  }
}

extern "C" void kernel_launch(void* const* d_in, const int* in_sizes, int n_in,
                              void* d_out, int out_size, void* d_ws, size_t ws_size,
                              hipStream_t stream) {
  const float* x   = (const float*)d_in[0];
  const float* wih = (const float*)d_in[1];
  const float* whh = (const float*)d_in[2];
  const float* bih = (const float*)d_in[3];
  const float* bhh = (const float*)d_in[4];
  const float* who = (const float*)d_in[5];
  const float* bho = (const float*)d_in[6];
  float* out = (float*)d_out;

  // ws: hbuf [2][16][16][2][512] u16 (1 MB) | flags 4096 u32 (16 KB) | partial 2 MB
  unsigned short* hbuf = (unsigned short*)d_ws;
  unsigned int* flags  = (unsigned int*)(hbuf + (size_t)2 * 262144);
  float* partial       = (float*)(flags + 4096);

  init_kernel<<<512, 256, 0, stream>>>((unsigned int*)hbuf, flags);
  rnn_persist<<<64, 256, 0, stream>>>(x, wih, whh, bih, bhh, who,
                                      hbuf, flags, partial);
  combine_kernel<<<512, 256, 0, stream>>>(partial, bho, out);
}